// Round 9
// baseline (748.915 us; speedup 1.0000x reference)
//
#include <hip/hip_runtime.h>
#include <hip/hip_bf16.h>

// B=4, N=256, F=64, H=256, A=16, T=3. BN=1024.
// SINGLE persistent kernel (grid=256, regular launch -- proven graph-safe in
// R5). Distributed-flag grid barrier: per-block padded arrive/release slots,
// equality-vs-round polling (poison-proof, no memset). Stages keep full
// parallelism (R7/R8 shapes). bf16 MFMA 16x16x32, BK=64 prefetch, padded LDS.
// Split hi/lo activations + dup-K weights. gi = Ehat@Wcomb + bih + deg*v2,
// Wcomb = msgW2@Wih via MFMA (exact), v2 = msgb2@Wih.

typedef unsigned short ushort_t;
typedef short bf8_t __attribute__((ext_vector_type(8)));
typedef float f4_t  __attribute__((ext_vector_type(4)));

#define NBLK 256
#define LDA 72

// ---- ushort offsets ----
#define UB_NFB     0          // [1024][64]
#define UB_PW1T    65536      // [256][64]
#define UB_PW2T    81920      // [256][512] dup
#define UB_WCATT   212992     // [1280][512] dup
#define UB_WIHT    868352     // [768][256]
#define UB_MSGW2S  1064960    // [256][256]
#define UB_WCOMBT  1130496    // [768][896]: per n: [Whi(256)|0|Whi|0|Wlo|0]
#define UB_X2      1818624    // [1024][512] hi|lo
#define UB_H2      2342912    // [1024][512] hi|lo
#define UB_EHAT    2867200    // [1024][896]: [Ehi|0|Elo|0|Ehi|0]
// ---- float offsets ----
#define F_PREB1    1892352    // 256
#define F_PREB2    1892608    // 256
#define F_BCAT     1892864    // 1280
#define F_BIH      1894144    // 768
#define F_ROW1     1894912    // 65536
#define F_ROB1     1960448    // 256
#define F_ROW2     1960704    // 4096
#define F_ROB2     1964800    // 16
#define F_V2       1964816    // 768
#define F_DEG      1965584    // 1024
#define F_H        1966608    // 262144
#define F_HCAT     2228752    // 1310720
#define F_GI       3539472    // 786432
#define F_FLAG     4325904    // 1
#define F_ARR      4325920    // 256*16 uints
#define F_REL      4330016    // 256*16 uints
#define F_GPART    4334112    // 32*256
#define F_END      4342304    // ~17.4 MB

// ---- conv index space ----
#define CV1 65536
#define CV2 81920
#define CV3 212992
#define CV4 868352
#define CV5 1064960
#define CV6 1130496
#define CV7 1204224
#define CV_TOTAL 1276688

__device__ __forceinline__ float bf2f(ushort_t u) {
    return __uint_as_float(((unsigned int)u) << 16);
}
__device__ __forceinline__ ushort_t f2b(float v) {
    __hip_bfloat16 b = __float2bfloat16(v);
    return *reinterpret_cast<ushort_t*>(&b);
}
__device__ __forceinline__ float relu(float v) { return v < 0.f ? 0.f : v; }
__device__ __forceinline__ float ld(const void* p, int i, int isf32) {
    return isf32 ? ((const float*)p)[i] : bf2f(((const ushort_t*)p)[i]);
}

// Distributed-flag grid barrier. Each slot is 64B-padded; equality polling
// against the monotonically increasing round -> 0xAA poison is harmless.
__device__ __forceinline__ void gridbar(unsigned* arr, unsigned* rel,
                                        int bid, unsigned round) {
    __syncthreads();
    const int t = threadIdx.x;
    if (bid == 0) {
        if (t > 0) {   // poll arrive slot t (distinct line per thread)
            while (__hip_atomic_load(&arr[t * 16], __ATOMIC_RELAXED,
                                     __HIP_MEMORY_SCOPE_AGENT) != round)
                __builtin_amdgcn_s_sleep(1);
        }
        __syncthreads();
        __threadfence();
        __hip_atomic_store(&rel[t * 16], round, __ATOMIC_RELAXED,
                           __HIP_MEMORY_SCOPE_AGENT);
    } else {
        if (t == 0) {
            __threadfence();
            __hip_atomic_store(&arr[bid * 16], round, __ATOMIC_RELAXED,
                               __HIP_MEMORY_SCOPE_AGENT);
            while (__hip_atomic_load(&rel[bid * 16], __ATOMIC_RELAXED,
                                     __HIP_MEMORY_SCOPE_AGENT) != round)
                __builtin_amdgcn_s_sleep(1);
            __threadfence();
        }
    }
    __syncthreads();
}

// acc += A[bm:+128,:K] @ Bt[bn:+128,:K]^T, BK=64 with VGPR prefetch.
__device__ __forceinline__ void mgemm_core(
    const ushort_t* __restrict__ A, const ushort_t* __restrict__ Bt,
    int K, int bm, int bn, ushort_t* As, ushort_t* Bs, f4_t acc[4][4])
{
    const int t = threadIdx.x;
    const int wave = t >> 6, lane = t & 63;
    const int ln = lane & 15, quad = lane >> 4;
    const int wm = (wave >> 1) * 64, wn = (wave & 1) * 64;
    const int sr = t >> 3, sc = (t & 7) << 3;

    bf8_t ga[4], gb[4];
#pragma unroll
    for (int r = 0; r < 4; ++r) {
        ga[r] = *(const bf8_t*)(&A[(bm + sr + r * 32) * K + sc]);
        gb[r] = *(const bf8_t*)(&Bt[(bn + sr + r * 32) * K + sc]);
    }
    for (int k0 = 0;;) {
        __syncthreads();
#pragma unroll
        for (int r = 0; r < 4; ++r) {
            *(bf8_t*)(&As[(sr + r * 32) * LDA + sc]) = ga[r];
            *(bf8_t*)(&Bs[(sr + r * 32) * LDA + sc]) = gb[r];
        }
        __syncthreads();
        const int kn = k0 + 64;
        if (kn < K) {
#pragma unroll
            for (int r = 0; r < 4; ++r) {
                ga[r] = *(const bf8_t*)(&A[(bm + sr + r * 32) * K + kn + sc]);
                gb[r] = *(const bf8_t*)(&Bt[(bn + sr + r * 32) * K + kn + sc]);
            }
        }
#pragma unroll
        for (int half = 0; half < 2; ++half) {
            bf8_t af[4], bfr[4];
#pragma unroll
            for (int i = 0; i < 4; ++i) {
                af[i]  = *(const bf8_t*)(&As[(wm + i * 16 + ln) * LDA + half * 32 + quad * 8]);
                bfr[i] = *(const bf8_t*)(&Bs[(wn + i * 16 + ln) * LDA + half * 32 + quad * 8]);
            }
#pragma unroll
            for (int mi = 0; mi < 4; ++mi)
#pragma unroll
                for (int ni = 0; ni < 4; ++ni)
                    acc[mi][ni] = __builtin_amdgcn_mfma_f32_16x16x32_bf16(
                        af[mi], bfr[ni], acc[mi][ni], 0, 0, 0);
        }
        k0 = kn;
        if (k0 >= K) break;
    }
}

__global__ __launch_bounds__(256) void mono_kernel(
    const void* nf, const void* p_adj,
    const void* preW1, const void* preb1, const void* preW2, const void* preb2,
    const void* msgW1, const void* msgb1, const void* msgW2, const void* msgb2,
    const void* gruWih, const void* gruWhh, const void* grubih, const void* grubhh,
    const void* roW1, const void* rob1, const void* roW2, const void* rob2,
    float* __restrict__ w, void* __restrict__ out)
{
    __shared__ __align__(16) ushort_t smem[2 * 128 * LDA];   // 36 KB
    ushort_t* As = smem;
    ushort_t* Bs = smem + 128 * LDA;
    const int bid = blockIdx.x, t = threadIdx.x;
    ushort_t* wb = (ushort_t*)w;
    const int* adj = (const int*)p_adj;
    unsigned* arr = (unsigned*)(w + F_ARR);
    unsigned* rel = (unsigned*)(w + F_REL);
    unsigned round = 0;
    const int wave = t >> 6, lane = t & 63;
    const int ln = lane & 15, quad = lane >> 4;
    const int wm = (wave >> 1) * 64, wn = (wave & 1) * 64;

    // ---- S0: dtype detect (block-local) ----
    int* cnt = (int*)smem;
    if (t == 0) *cnt = 0;
    __syncthreads();
    {
        const ushort_t* nf16 = (const ushort_t*)nf;
        int bad = 0;
        for (int i = 0; i < 8; ++i) {
            ushort_t u = nf16[(t * 8 + i) * 2];
            int ex = (u >> 7) & 0xFF;
            if ((u & 0x7fff) != 0 && (ex < 100 || ex > 140)) bad++;
        }
        atomicAdd(cnt, bad);
    }
    __syncthreads();
    const int f32 = (*cnt > 512) ? 1 : 0;
    __syncthreads();
    if (bid == 0 && t == 0) ((int*)(w + F_FLAG))[0] = f32;

    // ---- S1: convert/stage weights; block 0 also computes v2 ----
    for (int e = bid * 256 + t; e < CV_TOTAL; e += NBLK * 256) {
        if (e < CV1) {
            wb[UB_NFB + e] = f2b(ld(nf, e, f32));
        } else if (e < CV2) {
            int i = e - CV1; int n = i >> 6, k = i & 63;
            wb[UB_PW1T + i] = f2b(ld(preW1, k * 256 + n, f32));
        } else if (e < CV3) {
            int i = e - CV2; int n = i >> 9, k = i & 255;
            wb[UB_PW2T + i] = f2b(ld(preW2, k * 256 + n, f32));
        } else if (e < CV4) {
            int i = e - CV3; int n = i >> 9, k = i & 255;
            float v;
            if (n < 256)      v = ld(msgW1, k * 256 + n, f32);
            else if (n < 512) v = ld(msgW1, (256 + k) * 256 + (n - 256), f32);
            else              v = ld(gruWhh, k * 768 + (n - 512), f32);
            wb[UB_WCATT + i] = f2b(v);
        } else if (e < CV5) {
            int i = e - CV4; int n = i >> 8, k = i & 255;
            wb[UB_WIHT + i] = f2b(ld(gruWih, k * 768 + n, f32));
        } else if (e < CV6) {
            int i = e - CV5;
            wb[UB_MSGW2S + i] = f2b(ld(msgW2, i, f32));
        } else if (e < CV7) {
            int i = e - CV6; int n = i / 96, s = i - n * 96;
            int slot = (s < 32) ? (256 + s) : (s < 64) ? (544 + s - 32) : (832 + s - 64);
            wb[UB_WCOMBT + n * 896 + slot] = 0;
        } else {
            int f = e - CV7;
            float v;
            if (f < 256)        v = ld(preb1, f, f32);
            else if (f < 512)   v = ld(preb2, f - 256, f32);
            else if (f < 1792) {
                int c = f - 512;
                if (c < 256)      v = ld(msgb1, c, f32);
                else if (c < 512) v = 0.f;
                else              v = ld(grubhh, c - 512, f32);
            }
            else if (f < 2560)  v = ld(grubih, f - 1792, f32);
            else if (f < 68096) v = ld(roW1, f - 2560, f32);
            else if (f < 68352) v = ld(rob1, f - 68096, f32);
            else if (f < 72448) v = ld(roW2, f - 68352, f32);
            else                v = ld(rob2, f - 72448, f32);
            w[F_PREB1 + f] = v;
        }
    }
    if (bid == 1) {   // v2[n] = msgb2 . Wih[:,n] (parallel with staging)
        __shared__ float b2s[256];
        b2s[t] = ld(msgb2, t, f32);
        __syncthreads();
        for (int n = t; n < 768; n += 256) {
            float a = 0.f;
#pragma unroll 8
            for (int c = 0; c < 256; ++c) a += b2s[c] * ld(gruWih, c * 768 + n, f32);
            w[F_V2 + n] = a;
        }
    }
    gridbar(arr, rel, bid, ++round);

    // ---- S2: preB (blocks 0-7: pre1+pre2 row-chain; 8-19: Wcomb GEMM) ----
    if (bid < 8) {
        const int bm = bid * 128;
        for (int bnI = 0; bnI < 2; ++bnI) {
            f4_t acc[4][4] = {};
            mgemm_core(wb + UB_NFB, wb + UB_PW1T, 64, bm, bnI * 128, As, Bs, acc);
#pragma unroll
            for (int mi = 0; mi < 4; ++mi)
#pragma unroll
                for (int ni = 0; ni < 4; ++ni) {
                    int col = bnI * 128 + wn + ni * 16 + ln;
                    float bb = w[F_PREB1 + col];
#pragma unroll
                    for (int r = 0; r < 4; ++r) {
                        int row = bm + wm + mi * 16 + quad * 4 + r;
                        float v = relu(acc[mi][ni][r] + bb);
                        ushort_t hi = f2b(v);
                        wb[UB_X2 + row * 512 + col] = hi;
                        wb[UB_X2 + row * 512 + 256 + col] = f2b(v - bf2f(hi));
                    }
                }
        }
        __syncthreads();
        for (int bnI = 0; bnI < 2; ++bnI) {
            f4_t acc[4][4] = {};
            mgemm_core(wb + UB_X2, wb + UB_PW2T, 512, bm, bnI * 128, As, Bs, acc);
#pragma unroll
            for (int mi = 0; mi < 4; ++mi)
#pragma unroll
                for (int ni = 0; ni < 4; ++ni) {
                    int col = bnI * 128 + wn + ni * 16 + ln;
                    float bb = w[F_PREB2 + col];
#pragma unroll
                    for (int r = 0; r < 4; ++r) {
                        int row = bm + wm + mi * 16 + quad * 4 + r;
                        float v = acc[mi][ni][r] + bb;
                        w[F_H + row * 256 + col] = v;
                        ushort_t hi = f2b(v);
                        wb[UB_H2 + row * 512 + col] = hi;
                        wb[UB_H2 + row * 512 + 256 + col] = f2b(v - bf2f(hi));
                    }
                }
            __syncthreads();
        }
    } else if (bid < 20) {
        const int tile = bid - 8;
        const int bm = (tile / 6) * 128, bn = (tile % 6) * 128;
        f4_t acc[4][4] = {};
        mgemm_core(wb + UB_MSGW2S, wb + UB_WIHT, 256, bm, bn, As, Bs, acc);
#pragma unroll
        for (int mi = 0; mi < 4; ++mi)
#pragma unroll
            for (int ni = 0; ni < 4; ++ni) {
                int n = bn + wn + ni * 16 + ln;
#pragma unroll
                for (int r = 0; r < 4; ++r) {
                    int k = bm + wm + mi * 16 + quad * 4 + r;
                    float v = acc[mi][ni][r];
                    ushort_t hi = f2b(v);
                    ushort_t lo = f2b(v - bf2f(hi));
                    wb[UB_WCOMBT + n * 896 + k] = hi;
                    wb[UB_WCOMBT + n * 896 + 288 + k] = hi;
                    wb[UB_WCOMBT + n * 896 + 576 + k] = lo;
                }
            }
    }
    gridbar(arr, rel, bid, ++round);

    for (int it = 0; it < 3; ++it) {
        // ---- hcat GEMM: 80 tiles ----
        if (bid < 80) {
            const int bm = (bid / 10) * 128, bn = (bid % 10) * 128;
            f4_t acc[4][4] = {};
            mgemm_core(wb + UB_H2, wb + UB_WCATT, 512, bm, bn, As, Bs, acc);
#pragma unroll
            for (int mi = 0; mi < 4; ++mi)
#pragma unroll
                for (int ni = 0; ni < 4; ++ni) {
                    int col = bn + wn + ni * 16 + ln;
                    float bb = w[F_BCAT + col];
#pragma unroll
                    for (int r = 0; r < 4; ++r) {
                        int row = bm + wm + mi * 16 + quad * 4 + r;
                        w[F_HCAT + row * 1280 + col] = acc[mi][ni][r] + bb;
                    }
                }
        }
        gridbar(arr, rel, bid, ++round);

        // ---- msg: 4 rows/block ----
        {
            float* adjf = (float*)smem;
            const int r0 = bid * 4;
#pragma unroll
            for (int rr = 0; rr < 4; ++rr)
                adjf[rr * 256 + t] = (float)adj[(r0 + rr) * 256 + t];
            float hi_[4];
#pragma unroll
            for (int rr = 0; rr < 4; ++rr)
                hi_[rr] = w[F_HCAT + (r0 + rr) * 1280 + t];
            const float* hjb = w + F_HCAT + (r0 >> 8) * 256 * 1280 + 256;
            __syncthreads();
            float acc[4] = {}, cnt_[4] = {};
#pragma unroll 4
            for (int j = 0; j < 256; ++j) {
                float hjv = hjb[j * 1280 + t];
#pragma unroll
                for (int rr = 0; rr < 4; ++rr) {
                    float a = adjf[rr * 256 + j];
                    acc[rr] += a * relu(hi_[rr] + hjv);
                    cnt_[rr] += a;
                }
            }
#pragma unroll
            for (int rr = 0; rr < 4; ++rr) {
                const int row = r0 + rr;
                ushort_t h16 = f2b(acc[rr]);
                ushort_t l16 = f2b(acc[rr] - bf2f(h16));
                wb[UB_EHAT + row * 896 + t] = h16;
                wb[UB_EHAT + row * 896 + 288 + t] = l16;
                wb[UB_EHAT + row * 896 + 576 + t] = h16;
                if (t < 32) {
                    wb[UB_EHAT + row * 896 + 256 + t] = 0;
                    wb[UB_EHAT + row * 896 + 544 + t] = 0;
                    wb[UB_EHAT + row * 896 + 832 + t] = 0;
                    wb[UB_EHAT + row * 896 + 864 + t] = 0;
                }
                if (t == 0) w[F_DEG + row] = cnt_[rr];
            }
            __syncthreads();
        }
        gridbar(arr, rel, bid, ++round);

        // ---- gi GEMM: 48 tiles, + bih + deg*v2 ----
        if (bid < 48) {
            const int bm = (bid / 6) * 128, bn = (bid % 6) * 128;
            f4_t acc[4][4] = {};
            mgemm_core(wb + UB_EHAT, wb + UB_WCOMBT, 896, bm, bn, As, Bs, acc);
#pragma unroll
            for (int mi = 0; mi < 4; ++mi) {
#pragma unroll
                for (int r = 0; r < 4; ++r) {
                    int row = bm + wm + mi * 16 + quad * 4 + r;
                    float dg = w[F_DEG + row];
#pragma unroll
                    for (int ni = 0; ni < 4; ++ni) {
                        int col = bn + wn + ni * 16 + ln;
                        w[F_GI + row * 768 + col] =
                            acc[mi][ni][r] + w[F_BIH + col] + dg * w[F_V2 + col];
                    }
                }
            }
        }
        gridbar(arr, rel, bid, ++round);

        // ---- GRU: 4 rows/block, in-place h + H2 ----
#pragma unroll
        for (int rr = 0; rr < 4; ++rr) {
            const int row = bid * 4 + rr;
            const float* gir = w + F_GI + row * 768;
            const float* ghr = w + F_HCAT + row * 1280 + 512;
            float ir = gir[t], iz = gir[256 + t], in = gir[512 + t];
            float hr = ghr[t], hz = ghr[256 + t], hn = ghr[512 + t];
            float r = 1.f / (1.f + __expf(-(ir + hr)));
            float z = 1.f / (1.f + __expf(-(iz + hz)));
            float n = tanhf(in + r * hn);
            float ho = w[F_H + row * 256 + t];
            float hv = (1.f - z) * n + z * ho;
            w[F_H + row * 256 + t] = hv;
            ushort_t hb = f2b(hv);
            wb[UB_H2 + row * 512 + t] = hb;
            wb[UB_H2 + row * 512 + 256 + t] = f2b(hv - bf2f(hb));
        }
        gridbar(arr, rel, bid, ++round);
    }

    // ---- gsum: 32 blocks, partial column sums of h ----
    if (bid < 32) {
        const int b = bid >> 3, chunk = bid & 7;
        const float* hb = w + F_H + (b * 256 + chunk * 32) * 256;
        float s = 0.f;
#pragma unroll 8
        for (int i = 0; i < 32; ++i) s += hb[i * 256 + t];
        w[F_GPART + bid * 256 + t] = s;
    }
    gridbar(arr, rel, bid, ++round);

    // ---- out: 4 blocks, MLP ----
    if (bid < 4) {
        float* gl = (float*)smem;
        float* t1 = gl + 256;
        float g = 0.f;
#pragma unroll
        for (int c = 0; c < 8; ++c) g += w[F_GPART + (bid * 8 + c) * 256 + t];
        gl[t] = g;
        __syncthreads();
        float acc = w[F_ROB1 + t];
        for (int k = 0; k < 256; ++k) acc += gl[k] * w[F_ROW1 + k * 256 + t];
        t1[t] = relu(acc);
        __syncthreads();
        if (t < 16) {
            float q = w[F_ROB2 + t];
            for (int k = 0; k < 256; ++k) q += t1[k] * w[F_ROW2 + k * 16 + t];
            if (f32) ((float*)out)[bid * 16 + t] = q;
            else ((__hip_bfloat16*)out)[bid * 16 + t] = __float2bfloat16(q);
        }
    }
}

extern "C" void kernel_launch(void* const* d_in, const int* in_sizes, int n_in,
                              void* d_out, int out_size, void* d_ws, size_t ws_size,
                              hipStream_t stream) {
    float* w = (float*)d_ws;

    static const int dictSz[18]  = {65536,262144,16384,256,65536,256,131072,256,65536,256,
                                    196608,196608,768,768,65536,256,4096,16};
    static const int alphaSz[18] = {262144,196608,196608,768,768,131072,65536,256,256,
                                    65536,16384,65536,256,256,65536,4096,256,16};
    static const int alphaPos[18] = {9,0,10,12,11,13,5,7,6,8,2,1,4,3,14,16,15,17};
    bool dictOK = true, alphaOK = true;
    for (int i = 0; i < 18 && i < n_in; ++i) {
        if (in_sizes[i] != dictSz[i])  dictOK = false;
        if (in_sizes[i] != alphaSz[i]) alphaOK = false;
    }
    const void* P[18];
    for (int l = 0; l < 18; ++l) P[l] = d_in[(!dictOK && alphaOK) ? alphaPos[l] : l];

    mono_kernel<<<NBLK, 256, 0, stream>>>(
        P[0], P[1], P[2], P[3], P[4], P[5], P[6], P[7], P[8], P[9],
        P[10], P[11], P[12], P[13], P[14], P[15], P[16], P[17], w, d_out);
}